// Round 4
// baseline (444.160 us; speedup 1.0000x reference)
//
#include <hip/hip_runtime.h>
#include <cstdint>

#define BATCH 8
#define LQ 512
#define LK 2048
#define NH 16
#define DIM 64
#define HID 1024
#define NTOK (BATCH * LQ)   // 4096 tokens
#define NKT (LK / 64)       // 32 key tiles
#define KP 76               // LDS row pad: 152B = 38dw -> ~2-way max conflict on b128
#define SC 0.1803368801111204f    // 0.125 * log2(e): folded into Q at pack time
#define NEGM (-1.4426950408889634e8f)  // -1e8 * log2(e): key-mask in exp2 domain

typedef _Float16 f16x8 __attribute__((ext_vector_type(8)));
typedef __fp16 half2v __attribute__((ext_vector_type(2)));
typedef float f32x4 __attribute__((ext_vector_type(4)));

#define MFMA(a, b, c) __builtin_amdgcn_mfma_f32_16x16x32_f16((a), (b), (c), 0, 0, 0)

__device__ __forceinline__ f16x8 ld8(const _Float16* p) { return *(const f16x8*)p; }

// async global->LDS, 16B per lane; lds dst is wave-uniform base (HW adds lane*16)
__device__ __forceinline__ void gl_lds16(const void* g, void* l) {
  __builtin_amdgcn_global_load_lds(
      (const __attribute__((address_space(1))) uint32_t*)g,
      (__attribute__((address_space(3))) uint32_t*)l, 16, 0, 0);
}

// producer-side LDS flush + barrier that does NOT drain vmcnt: in-flight
// global->VGPR loads survive (HK/m194 idiom).
__device__ __forceinline__ void lds_barrier() {
  asm volatile("s_waitcnt lgkmcnt(0)" ::: "memory");
  __builtin_amdgcn_s_barrier();
}

// 8 consecutive fp32 -> fp16 fragment (RTE scalar casts)
__device__ __forceinline__ f16x8 cvt8(const float* p) {
  const float4 a = *(const float4*)p;
  const float4 b = *(const float4*)(p + 4);
  f16x8 v;
  v[0] = (_Float16)a.x; v[1] = (_Float16)a.y; v[2] = (_Float16)a.z; v[3] = (_Float16)a.w;
  v[4] = (_Float16)b.x; v[5] = (_Float16)b.y; v[6] = (_Float16)b.z; v[7] = (_Float16)b.w;
  return v;
}

// pack 4 fp32 -> 4 fp16 (2x v_cvt_pkrtz) for ds_write_b64
__device__ __forceinline__ uint2 pk4(float a, float b, float c, float d) {
  union { half2v h2[2]; uint2 u; } t;
  t.h2[0] = __builtin_amdgcn_cvt_pkrtz(a, b);
  t.h2[1] = __builtin_amdgcn_cvt_pkrtz(c, d);
  return t.u;
}

// two float4 -> f16x8 via pkrtz
__device__ __forceinline__ f16x8 pk8(float4 a, float4 b) {
  union { half2v h2[4]; f16x8 v; } t;
  t.h2[0] = __builtin_amdgcn_cvt_pkrtz(a.x, a.y);
  t.h2[1] = __builtin_amdgcn_cvt_pkrtz(a.z, a.w);
  t.h2[2] = __builtin_amdgcn_cvt_pkrtz(b.x, b.y);
  t.h2[3] = __builtin_amdgcn_cvt_pkrtz(b.z, b.w);
  return t.v;
}

// ---------------------------------------------------------------------------
// Fully fused attention: Q/K/V projections + flash attention in one kernel.
// ROUND 4 = ROUND 3 STRUCTURE, SPILL FIX ONLY. Round 3's __launch_bounds__
// (512,4) capped VGPR at 64 -> scratch spills (WRITE_SIZE 8->14MB, 300us).
// The 2-blocks/CU goal was otherwise achieved (occupancy 41%). Fix: bounds
// (512,2) -- compiler allocates naturally (~75-85 VGPR, no spill); since
// that is <=128, HW still co-schedules 4 waves/SIMD = 2 blocks/CU (LDS
// 65KB x 2 = 130KB <= 160KB). Decoupled per-block barriers give the TLP.
// Per (b,h) x 128-q block, grid (128,4), 512 thr / 8 waves, 16 q per wave.
// Wave-specialized projections (waves 0-3: K, 4-7: V), reg-staged X,
// double-buffered Kl/Vl, one lgkmcnt-only barrier/tile, setprio on MFMA,
// KP=76 pad (~2-way max conflict on the b128 fragment reads).
// ---------------------------------------------------------------------------
__global__ __launch_bounds__(512, 2) void attn_kernel(
    const float* __restrict__ Xq, const float* __restrict__ Xk,
    const float* __restrict__ Wq, const float* __restrict__ Wk,
    const float* __restrict__ Wv, const float* __restrict__ kg_mask,
    _Float16* __restrict__ ctx) {
  __shared__ __align__(16) _Float16 Kl[2][64 * KP];  // 19 KB: [key][e]
  __shared__ __align__(16) _Float16 Vl[2][64 * KP];  // 19 KB: [d][key]
  __shared__ __align__(16) _Float16 Pl[8][16 * KP];  // 19 KB: per-wave Q/P transpose
  __shared__ __align__(16) float    Ml[LK];          // 8 KB:  (1-mask)*NEGM
  const int tid = threadIdx.x;
  const int wave = tid >> 6, lane = tid & 63, l16 = lane & 15, quad = lane >> 4;
  const int kw = wave & 3;  // row-group for X/K/V projection work
  const int b = blockIdx.x >> 4, h = blockIdx.x & 15;
  const int qbase = blockIdx.y * 128;
  const float* Xg = Xk + (size_t)b * LK * HID + h * 64;  // key-side X, this head's cols
  const float* mg = kg_mask + (size_t)b * LK;

  // X register staging: lane (quad,l16) of wave kw holds row kw*16+l16,
  // logical chunks 2q,2q+1 (floats 8q..8q+7) and 2q+8,2q+9 (8q+32..8q+39).
  const float* xrow0 = Xg + (size_t)(kw * 16 + l16) * HID + quad * 8;
  float4 xf0, xf1, xf2, xf3;
  auto loadX = [&](int kt) {
    const float* xr = xrow0 + (size_t)kt * HID;
    xf0 = *(const float4*)(xr);
    xf1 = *(const float4*)(xr + 4);
    xf2 = *(const float4*)(xr + 32);
    xf3 = *(const float4*)(xr + 36);
  };
  loadX(0);  // in flight across the whole prologue

  // mask pre-scale into LDS: 512 threads x float4 covers LK=2048 exactly.
  {
    const float4 m4 = *(const float4*)(mg + tid * 4);
    float4 mo;
    mo.x = (1.f - m4.x) * NEGM;
    mo.y = (1.f - m4.y) * NEGM;
    mo.z = (1.f - m4.z) * NEGM;
    mo.w = (1.f - m4.w) * NEGM;
    *(float4*)(Ml + tid * 4) = mo;
  }

  // ---- fused Q projection: D[d_out][q] = Wq . Xq^T, scaled by SC ----
  // Each wave: 16 queries (qbase + wave*16 + l16).
  f16x8 aq0, aq1;
  {
    f16x8 wq0[4], wq1[4];
#pragma unroll
    for (int nt = 0; nt < 4; ++nt) {
      const float* wp = Wq + (nt * 16 + l16) * DIM + quad * 8;
      wq0[nt] = cvt8(wp);
      wq1[nt] = cvt8(wp + 32);
    }
    const int qg = qbase + wave * 16 + l16;
    const float* xpq = Xq + (size_t)(b * LQ + qg) * HID + h * 64 + quad * 8;
    const f16x8 bq0 = cvt8(xpq), bq1 = cvt8(xpq + 32);
#pragma unroll
    for (int nt = 0; nt < 4; ++nt) {
      f32x4 d = {0.f, 0.f, 0.f, 0.f};
      d = MFMA(wq0[nt], bq0, d);
      d = MFMA(wq1[nt], bq1, d);
      *(uint2*)&Pl[wave][l16 * KP + nt * 16 + quad * 4] =
          pk4(d[0] * SC, d[1] * SC, d[2] * SC, d[3] * SC);
    }
    aq0 = ld8(&Pl[wave][l16 * KP + quad * 8]);
    aq1 = ld8(&Pl[wave][l16 * KP + 32 + quad * 8]);
  }

  // ---- projection weight fragments, once per block: waves 0-3 hold Wk
  // (A-operand of K proj), waves 4-7 hold Wv (B-operand of V proj). ----
  const float* Wsel = (wave < 4) ? Wk : Wv;
  f16x8 aw0[4], aw1[4];
#pragma unroll
  for (int nt = 0; nt < 4; ++nt) {
    const float* wp = Wsel + (nt * 16 + l16) * DIM + quad * 8;
    aw0[nt] = cvt8(wp);
    aw1[nt] = cvt8(wp + 32);
  }

  const f32x4 z4 = {0.f, 0.f, 0.f, 0.f};

  // ---- proj(0) into buffer 0 (xf holds X[0]; compiler waits vmcnt here) ----
  {
    const f16x8 bx0 = pk8(xf0, xf1), bx1 = pk8(xf2, xf3);
    if (wave < 4) {
#pragma unroll
      for (int nt = 0; nt < 4; ++nt) {
        f32x4 d = z4;
        d = MFMA(aw0[nt], bx0, d);
        d = MFMA(aw1[nt], bx1, d);
        *(uint2*)&Kl[0][(kw * 16 + l16) * KP + nt * 16 + quad * 4] =
            pk4(d[0], d[1], d[2], d[3]);
      }
    } else {
#pragma unroll
      for (int dt = 0; dt < 4; ++dt) {
        f32x4 d = z4;
        d = MFMA(bx0, aw0[dt], d);
        d = MFMA(bx1, aw1[dt], d);
        *(uint2*)&Vl[0][(dt * 16 + l16) * KP + kw * 16 + quad * 4] =
            pk4(d[0], d[1], d[2], d[3]);
      }
    }
  }
  loadX(64);      // X[1] in flight across the barrier
  lds_barrier();  // publishes Ml + KV[0]; X loads NOT drained

  f32x4 o[4];
  float l_run = 0.f;
#pragma unroll
  for (int i = 0; i < 4; ++i) o[i] = z4;

  for (int t = 0; t < NKT; ++t) {
    const int buf = t & 1;
    const int kt = t * 64;

    // ---- proj(t+1) into buf^1 (reads nothing of buf; races nothing) ----
    if (t + 1 < NKT) {
      const f16x8 bx0 = pk8(xf0, xf1), bx1 = pk8(xf2, xf3);  // counted vmcnt wait
      if (wave < 4) {
#pragma unroll
        for (int nt = 0; nt < 4; ++nt) {
          f32x4 d = z4;
          d = MFMA(aw0[nt], bx0, d);
          d = MFMA(aw1[nt], bx1, d);
          *(uint2*)&Kl[buf ^ 1][(kw * 16 + l16) * KP + nt * 16 + quad * 4] =
              pk4(d[0], d[1], d[2], d[3]);
        }
      } else {
#pragma unroll
        for (int dt = 0; dt < 4; ++dt) {
          f32x4 d = z4;
          d = MFMA(bx0, aw0[dt], d);
          d = MFMA(bx1, aw1[dt], d);
          *(uint2*)&Vl[buf ^ 1][(dt * 16 + l16) * KP + kw * 16 + quad * 4] =
              pk4(d[0], d[1], d[2], d[3]);
        }
      }
      if (t + 2 < NKT) loadX(kt + 128);  // X[t+2]: in flight across next barrier
    }

    // mask from LDS (pre-scaled); quad lanes broadcast the same float4
    float4 mv[4];
#pragma unroll
    for (int nt = 0; nt < 4; ++nt)
      mv[nt] = *(const float4*)(Ml + kt + nt * 16 + quad * 4);

    // S^T = K.Q^T : D[key=nt*16+quad*4+r][q=l16]; P = exp2(S + mask)
    float p[4][4];
    __builtin_amdgcn_s_setprio(1);
#pragma unroll
    for (int nt = 0; nt < 4; ++nt) {
      const f16x8 kb0 = ld8(&Kl[buf][(nt * 16 + l16) * KP + quad * 8]);
      const f16x8 kb1 = ld8(&Kl[buf][(nt * 16 + l16) * KP + 32 + quad * 8]);
      f32x4 s = z4;
      s = MFMA(kb0, aq0, s);
      s = MFMA(kb1, aq1, s);
      const float e0 = __builtin_amdgcn_exp2f(s[0] + mv[nt].x);
      const float e1 = __builtin_amdgcn_exp2f(s[1] + mv[nt].y);
      const float e2 = __builtin_amdgcn_exp2f(s[2] + mv[nt].z);
      const float e3 = __builtin_amdgcn_exp2f(s[3] + mv[nt].w);
      l_run += (e0 + e1) + (e2 + e3);
      p[nt][0] = e0; p[nt][1] = e1; p[nt][2] = e2; p[nt][3] = e3;
    }
    __builtin_amdgcn_s_setprio(0);

    // P: C-layout -> A-layout, per-wave LDS round trip
#pragma unroll
    for (int nt = 0; nt < 4; ++nt)
      *(uint2*)&Pl[wave][l16 * KP + nt * 16 + quad * 4] =
          pk4(p[nt][0], p[nt][1], p[nt][2], p[nt][3]);
    const f16x8 ap0 = ld8(&Pl[wave][l16 * KP + quad * 8]);
    const f16x8 ap1 = ld8(&Pl[wave][l16 * KP + 32 + quad * 8]);

    // O^T += V.P^T : D[d=dt*16+quad*4+r][q=l16]
    __builtin_amdgcn_s_setprio(1);
#pragma unroll
    for (int dt = 0; dt < 4; ++dt) {
      const f16x8 vb0 = ld8(&Vl[buf][(dt * 16 + l16) * KP + quad * 8]);
      const f16x8 vb1 = ld8(&Vl[buf][(dt * 16 + l16) * KP + 32 + quad * 8]);
      o[dt] = MFMA(vb0, ap0, o[dt]);
      o[dt] = MFMA(vb1, ap1, o[dt]);
    }
    __builtin_amdgcn_s_setprio(0);

    lds_barrier();  // publishes KV[t+1]; guards buf reuse; X loads survive
  }

  // row-sum: lane covers its quad's 16 keys; finish across quads
  float s = l_run;
  s += __shfl_xor(s, 16);
  s += __shfl_xor(s, 32);
  const float inv = 1.f / s;
  // ctx (token, h*64+d): lane's 4 d-values contiguous -> packed 8B stores
  {
    const int qg = qbase + wave * 16 + l16;
    _Float16* base = ctx + (size_t)(b * LQ + qg) * HID + h * 64;
#pragma unroll
    for (int dt = 0; dt < 4; ++dt)
      *(uint2*)(base + dt * 16 + quad * 4) =
          pk4(o[dt][0] * inv, o[dt][1] * inv, o[dt][2] * inv, o[dt][3] * inv);
  }
}

// ---------------------------------------------------------------------------
// W_lin fp32 -> fp16 (once; 2MB result stays L2-resident for linear_kernel)
// ---------------------------------------------------------------------------
__global__ __launch_bounds__(256) void wconv_kernel(const float* __restrict__ W,
                                                    _Float16* __restrict__ Wh) {
  const int i = blockIdx.x * 256 + threadIdx.x;
  const float4 v = ((const float4*)W)[i];
  ((uint2*)Wh)[i] = pk4(v.x, v.y, v.z, v.w);
}

// ---------------------------------------------------------------------------
// lin = ctx @ Wh^T + b; X = erf-GELU(lin) + resid. 128x128 tile, 512 threads
// (8 waves as 2x4), BK=64, double-buffered global_load_lds, 1 barrier/chunk.
// ---------------------------------------------------------------------------
__global__ __launch_bounds__(512) void linear_kernel(const _Float16* __restrict__ A,
                                                     const _Float16* __restrict__ Wh,
                                                     const float* __restrict__ bias,
                                                     const float* __restrict__ resid,
                                                     float* __restrict__ Xout) {
  __shared__ __align__(16) _Float16 Al[2][128 * 64];
  __shared__ __align__(16) _Float16 Bl[2][128 * 64];
  const int tid = threadIdx.x;
  const int wave = tid >> 6, lane = tid & 63, l16 = lane & 15, quad = lane >> 4;
  const int wm = wave >> 2, wn = wave & 3;
  const int nbase = blockIdx.x * 128, mbase = blockIdx.y * 128;
  const int srow = wave * 16 + (lane >> 3);
  const int sc = lane & 7;

  auto stage = [&](int kk, int nbuf) {
#pragma unroll
    for (int i = 0; i < 2; ++i) {
      const int row = srow + i * 8;
      const int c = sc ^ (row & 7);
      gl_lds16(A + (size_t)(mbase + row) * HID + kk + c * 8,
               &Al[nbuf][(wave * 16 + i * 8) * 64]);
      gl_lds16(Wh + (size_t)(nbase + row) * HID + kk + c * 8,
               &Bl[nbuf][(wave * 16 + i * 8) * 64]);
    }
  };

  const f32x4 z4 = {0.f, 0.f, 0.f, 0.f};
  f32x4 acc[4][2];
#pragma unroll
  for (int mt = 0; mt < 4; ++mt)
#pragma unroll
    for (int nt = 0; nt < 2; ++nt) acc[mt][nt] = z4;

  stage(0, 0);
  for (int t = 0; t < HID / 64; ++t) {
    const int buf = t & 1;
    __syncthreads();
    if (t + 1 < HID / 64) stage((t + 1) * 64, buf ^ 1);
    const int sw = l16 & 7;
    f16x8 b0[2], b1[2];
#pragma unroll
    for (int nt = 0; nt < 2; ++nt) {
      const int brow = wn * 32 + nt * 16 + l16;
      b0[nt] = ld8(&Bl[buf][brow * 64 + (quad ^ sw) * 8]);
      b1[nt] = ld8(&Bl[buf][brow * 64 + ((quad + 4) ^ sw) * 8]);
    }
#pragma unroll
    for (int mt = 0; mt < 4; ++mt) {
      const int arow = wm * 64 + mt * 16 + l16;
      const f16x8 a0 = ld8(&Al[buf][arow * 64 + (quad ^ sw) * 8]);
      const f16x8 a1 = ld8(&Al[buf][arow * 64 + ((quad + 4) ^ sw) * 8]);
#pragma unroll
      for (int nt = 0; nt < 2; ++nt) {
        acc[mt][nt] = MFMA(a0, b0[nt], acc[mt][nt]);
        acc[mt][nt] = MFMA(a1, b1[nt], acc[mt][nt]);
      }
    }
  }
#pragma unroll
  for (int nt = 0; nt < 2; ++nt) {
    const int col = nbase + wn * 32 + nt * 16 + l16;
    const float bv = bias[col];
#pragma unroll
    for (int mt = 0; mt < 4; ++mt) {
#pragma unroll
      for (int r = 0; r < 4; ++r) {
        const int row = mbase + wm * 64 + mt * 16 + quad * 4 + r;
        const float v = acc[mt][nt][r] + bv;
        const float g = 0.5f * v * (1.f + erff(v * 0.70710678118654752f));
        Xout[(size_t)row * HID + col] = g + resid[(size_t)row * HID + col];
      }
    }
  }
}

// ---------------------------------------------------------------------------
// LayerNorm over HID=1024 per token row.
// ---------------------------------------------------------------------------
__global__ __launch_bounds__(256) void ln_kernel(const float* __restrict__ X,
                                                 const float* __restrict__ gamma,
                                                 const float* __restrict__ beta,
                                                 float* __restrict__ out) {
  const int row = blockIdx.x, tid = threadIdx.x;
  const int lane = tid & 63, wave = tid >> 6;
  const float4 v = *(const float4*)(X + (size_t)row * HID + tid * 4);
  float s1 = v.x + v.y + v.z + v.w;
  float s2 = v.x * v.x + v.y * v.y + v.z * v.z + v.w * v.w;
#pragma unroll
  for (int off = 1; off < 64; off <<= 1) {
    s1 += __shfl_xor(s1, off);
    s2 += __shfl_xor(s2, off);
  }
  __shared__ float r1[4], r2[4];
  if (lane == 0) { r1[wave] = s1; r2[wave] = s2; }
  __syncthreads();
  s1 = r1[0] + r1[1] + r1[2] + r1[3];
  s2 = r2[0] + r2[1] + r2[2] + r2[3];
  const float mu = s1 * (1.f / HID);
  const float var = s2 * (1.f / HID) - mu * mu;
  const float rstd = rsqrtf(var + 1e-5f);
  const float4 g = *(const float4*)(gamma + tid * 4);
  const float4 be = *(const float4*)(beta + tid * 4);
  float4 ov;
  ov.x = (v.x - mu) * rstd * g.x + be.x;
  ov.y = (v.y - mu) * rstd * g.y + be.y;
  ov.z = (v.z - mu) * rstd * g.z + be.z;
  ov.w = (v.w - mu) * rstd * g.w + be.w;
  *(float4*)(out + (size_t)row * HID + tid * 4) = ov;
}

// ---------------------------------------------------------------------------
// Workspace:
//   ctx fp16 [ 0, 8M)
//   Xb  fp32 [ 8M,24M)
//   Wh  fp16 [24M,26M)
// ---------------------------------------------------------------------------
extern "C" void kernel_launch(void* const* d_in, const int* in_sizes, int n_in,
                              void* d_out, int out_size, void* d_ws, size_t ws_size,
                              hipStream_t stream) {
  (void)in_sizes; (void)n_in; (void)out_size; (void)ws_size;
  const float* input_embed = (const float*)d_in[0];
  const float* kg_embed    = (const float*)d_in[1];
  // d_in[2] = input_mask: additive per-query constant -> softmax-invariant, unused
  const float* kg_mask = (const float*)d_in[3];
  const float* Wq    = (const float*)d_in[4];
  const float* Wk    = (const float*)d_in[5];
  const float* Wv    = (const float*)d_in[6];
  const float* W_lin = (const float*)d_in[7];
  const float* b_lin = (const float*)d_in[8];
  const float* gamma = (const float*)d_in[9];
  const float* beta  = (const float*)d_in[10];

  char* ws = (char*)d_ws;
  _Float16* ctx = (_Float16*)(ws);
  float*    Xb  = (float*)(ws + (8u << 20));
  _Float16* Wh  = (_Float16*)(ws + (24u << 20));

  attn_kernel<<<dim3(128, 4), dim3(512), 0, stream>>>(input_embed, kg_embed, Wq, Wk, Wv,
                                                      kg_mask, ctx);
  wconv_kernel<<<dim3(1024), dim3(256), 0, stream>>>(W_lin, Wh);
  linear_kernel<<<dim3(8, 32), dim3(512), 0, stream>>>(ctx, Wh, b_lin, input_embed, Xb);
  ln_kernel<<<dim3(NTOK), dim3(256), 0, stream>>>(Xb, gamma, beta, (float*)d_out);
}

// Round 5
// 316.535 us; speedup vs baseline: 1.4032x; 1.4032x over previous
//
#include <hip/hip_runtime.h>
#include <cstdint>

#define BATCH 8
#define LQ 512
#define LK 2048
#define NH 16
#define DIM 64
#define HID 1024
#define NTOK (BATCH * LQ)   // 4096 tokens
#define NKT (LK / 64)       // 32 key tiles
#define KP 76               // LDS pad: 38dw stride -> 16 distinct bank-starts (~2-way max)
#define SC 0.1803368801111204f    // 0.125 * log2(e): folded into Q at pack time
#define NEGM (-1.4426950408889634e8f)  // -1e8 * log2(e): key-mask in exp2 domain

typedef _Float16 f16x8 __attribute__((ext_vector_type(8)));
typedef __fp16 half2v __attribute__((ext_vector_type(2)));
typedef float f32x4 __attribute__((ext_vector_type(4)));

#define MFMA(a, b, c) __builtin_amdgcn_mfma_f32_16x16x32_f16((a), (b), (c), 0, 0, 0)

__device__ __forceinline__ f16x8 ld8(const _Float16* p) { return *(const f16x8*)p; }

// async global->LDS, 16B per lane; lds dst is wave-uniform base (HW adds lane*16)
__device__ __forceinline__ void gl_lds16(const void* g, void* l) {
  __builtin_amdgcn_global_load_lds(
      (const __attribute__((address_space(1))) uint32_t*)g,
      (__attribute__((address_space(3))) uint32_t*)l, 16, 0, 0);
}

// producer-side LDS flush + barrier that does NOT drain vmcnt: in-flight
// global->VGPR loads survive (HK/m194 idiom).
__device__ __forceinline__ void lds_barrier() {
  asm volatile("s_waitcnt lgkmcnt(0)" ::: "memory");
  __builtin_amdgcn_s_barrier();
}

// 8 consecutive fp32 -> fp16 fragment (RTE scalar casts)
__device__ __forceinline__ f16x8 cvt8(const float* p) {
  const float4 a = *(const float4*)p;
  const float4 b = *(const float4*)(p + 4);
  f16x8 v;
  v[0] = (_Float16)a.x; v[1] = (_Float16)a.y; v[2] = (_Float16)a.z; v[3] = (_Float16)a.w;
  v[4] = (_Float16)b.x; v[5] = (_Float16)b.y; v[6] = (_Float16)b.z; v[7] = (_Float16)b.w;
  return v;
}

// pack 4 fp32 -> 4 fp16 (2x v_cvt_pkrtz) for ds_write_b64
__device__ __forceinline__ uint2 pk4(float a, float b, float c, float d) {
  union { half2v h2[2]; uint2 u; } t;
  t.h2[0] = __builtin_amdgcn_cvt_pkrtz(a, b);
  t.h2[1] = __builtin_amdgcn_cvt_pkrtz(c, d);
  return t.u;
}

// two float4 -> f16x8 via pkrtz
__device__ __forceinline__ f16x8 pk8(float4 a, float4 b) {
  union { half2v h2[4]; f16x8 v; } t;
  t.h2[0] = __builtin_amdgcn_cvt_pkrtz(a.x, a.y);
  t.h2[1] = __builtin_amdgcn_cvt_pkrtz(a.z, a.w);
  t.h2[2] = __builtin_amdgcn_cvt_pkrtz(b.x, b.y);
  t.h2[3] = __builtin_amdgcn_cvt_pkrtz(b.z, b.w);
  return t.v;
}

// ---------------------------------------------------------------------------
// Fully fused attention: Q/K/V projections + flash attention in one kernel.
// ROUND 5 = ROUND 2 STRUCTURE (verified 79.2us) + KP=76 pad ONLY.
// Rounds 3/4 proved the 128-q/(128,4) restructure is a latency trap (per-tile
// critical path doesn't shrink with per-wave work; X L2 locality dies; 2
// dispatch rounds serialize) -- reverted. KP 72->76 makes the b128 fragment
// reads' bank-starts (6*l16+4*quad) mod 32 hit 16 distinct banks (~2-way,
// free per m136) vs 8-way at 72, targeting the measured 8.5M conflict cycles.
// Per (b,h) x 256-q block: 512 thr / 8 waves, grid (128,2) = 256 blocks =
// 1/CU. Wave-specialized projections (waves 0-3: K, 4-7: V), reg-staged X,
// double-buffered Kl/Vl, ONE lgkmcnt-only barrier per tile, setprio on MFMA.
// ---------------------------------------------------------------------------
__global__ __launch_bounds__(512, 2) void attn_kernel(
    const float* __restrict__ Xq, const float* __restrict__ Xk,
    const float* __restrict__ Wq, const float* __restrict__ Wk,
    const float* __restrict__ Wv, const float* __restrict__ kg_mask,
    _Float16* __restrict__ ctx) {
  __shared__ __align__(16) _Float16 Kl[2][64 * KP];    // 19 KB: [key][e]
  __shared__ __align__(16) _Float16 Vl[2][64 * KP];    // 19 KB: [d][key]
  __shared__ __align__(16) _Float16 Pl[8][2][16 * KP]; // 38 KB: per-wave/qt P transpose
  __shared__ __align__(16) float    Ml[LK];            // 8 KB:  (1-mask)*NEGM
  const int tid = threadIdx.x;
  const int wave = tid >> 6, lane = tid & 63, l16 = lane & 15, quad = lane >> 4;
  const int kw = wave & 3;  // row-group for X/K/V projection work
  const int b = blockIdx.x >> 4, h = blockIdx.x & 15;
  const int qbase = blockIdx.y * 256;
  const float* Xg = Xk + (size_t)b * LK * HID + h * 64;  // key-side X, this head's cols
  const float* mg = kg_mask + (size_t)b * LK;

  // X register staging: lane (quad,l16) of wave kw holds row kw*16+l16,
  // logical chunks 2q,2q+1 (floats 8q..8q+7) and 2q+8,2q+9 (8q+32..8q+39).
  const float* xrow0 = Xg + (size_t)(kw * 16 + l16) * HID + quad * 8;
  float4 xf0, xf1, xf2, xf3;
  auto loadX = [&](int kt) {
    const float* xr = xrow0 + (size_t)kt * HID;
    xf0 = *(const float4*)(xr);
    xf1 = *(const float4*)(xr + 4);
    xf2 = *(const float4*)(xr + 32);
    xf3 = *(const float4*)(xr + 36);
  };
  loadX(0);  // in flight across the whole prologue

  // mask pre-scale into LDS: 512 threads x float4 covers LK=2048 exactly.
  {
    const float4 m4 = *(const float4*)(mg + tid * 4);
    float4 mo;
    mo.x = (1.f - m4.x) * NEGM;
    mo.y = (1.f - m4.y) * NEGM;
    mo.z = (1.f - m4.z) * NEGM;
    mo.w = (1.f - m4.w) * NEGM;
    *(float4*)(Ml + tid * 4) = mo;
  }

  // ---- fused Q projection: D[d_out][q] = Wq . Xq^T, scaled by SC ----
  f16x8 aq0[2], aq1[2];
  {
    f16x8 wq0[4], wq1[4];
#pragma unroll
    for (int nt = 0; nt < 4; ++nt) {
      const float* wp = Wq + (nt * 16 + l16) * DIM + quad * 8;
      wq0[nt] = cvt8(wp);
      wq1[nt] = cvt8(wp + 32);
    }
#pragma unroll
    for (int qt = 0; qt < 2; ++qt) {
      const int qg = qbase + wave * 32 + qt * 16 + l16;
      const float* xpq = Xq + (size_t)(b * LQ + qg) * HID + h * 64 + quad * 8;
      const f16x8 bq0 = cvt8(xpq), bq1 = cvt8(xpq + 32);
#pragma unroll
      for (int nt = 0; nt < 4; ++nt) {
        f32x4 d = {0.f, 0.f, 0.f, 0.f};
        d = MFMA(wq0[nt], bq0, d);
        d = MFMA(wq1[nt], bq1, d);
        *(uint2*)&Pl[wave][qt][l16 * KP + nt * 16 + quad * 4] =
            pk4(d[0] * SC, d[1] * SC, d[2] * SC, d[3] * SC);
      }
      aq0[qt] = ld8(&Pl[wave][qt][l16 * KP + quad * 8]);
      aq1[qt] = ld8(&Pl[wave][qt][l16 * KP + 32 + quad * 8]);
    }
  }

  // ---- projection weight fragments, once per block: waves 0-3 hold Wk
  // (A-operand of K proj), waves 4-7 hold Wv (B-operand of V proj). ----
  const float* Wsel = (wave < 4) ? Wk : Wv;
  f16x8 aw0[4], aw1[4];
#pragma unroll
  for (int nt = 0; nt < 4; ++nt) {
    const float* wp = Wsel + (nt * 16 + l16) * DIM + quad * 8;
    aw0[nt] = cvt8(wp);
    aw1[nt] = cvt8(wp + 32);
  }

  const f32x4 z4 = {0.f, 0.f, 0.f, 0.f};

  // ---- proj(0) into buffer 0 (xf holds X[0]; compiler waits vmcnt here) ----
  {
    const f16x8 bx0 = pk8(xf0, xf1), bx1 = pk8(xf2, xf3);
    if (wave < 4) {
#pragma unroll
      for (int nt = 0; nt < 4; ++nt) {
        f32x4 d = z4;
        d = MFMA(aw0[nt], bx0, d);
        d = MFMA(aw1[nt], bx1, d);
        *(uint2*)&Kl[0][(kw * 16 + l16) * KP + nt * 16 + quad * 4] =
            pk4(d[0], d[1], d[2], d[3]);
      }
    } else {
#pragma unroll
      for (int dt = 0; dt < 4; ++dt) {
        f32x4 d = z4;
        d = MFMA(bx0, aw0[dt], d);
        d = MFMA(bx1, aw1[dt], d);
        *(uint2*)&Vl[0][(dt * 16 + l16) * KP + kw * 16 + quad * 4] =
            pk4(d[0], d[1], d[2], d[3]);
      }
    }
  }
  loadX(64);      // X[1] in flight across the barrier
  lds_barrier();  // publishes Ml + KV[0]; X loads NOT drained

  f32x4 o[2][4];
  float l_run[2] = {0.f, 0.f};
#pragma unroll
  for (int qt = 0; qt < 2; ++qt)
#pragma unroll
    for (int i = 0; i < 4; ++i) o[qt][i] = z4;

  for (int t = 0; t < NKT; ++t) {
    const int buf = t & 1;
    const int kt = t * 64;

    // ---- proj(t+1) into buf^1 (reads nothing of buf; races nothing) ----
    if (t + 1 < NKT) {
      const f16x8 bx0 = pk8(xf0, xf1), bx1 = pk8(xf2, xf3);  // counted vmcnt wait
      if (wave < 4) {
#pragma unroll
        for (int nt = 0; nt < 4; ++nt) {
          f32x4 d = z4;
          d = MFMA(aw0[nt], bx0, d);
          d = MFMA(aw1[nt], bx1, d);
          *(uint2*)&Kl[buf ^ 1][(kw * 16 + l16) * KP + nt * 16 + quad * 4] =
              pk4(d[0], d[1], d[2], d[3]);
        }
      } else {
#pragma unroll
        for (int dt = 0; dt < 4; ++dt) {
          f32x4 d = z4;
          d = MFMA(bx0, aw0[dt], d);
          d = MFMA(bx1, aw1[dt], d);
          *(uint2*)&Vl[buf ^ 1][(dt * 16 + l16) * KP + kw * 16 + quad * 4] =
              pk4(d[0], d[1], d[2], d[3]);
        }
      }
      if (t + 2 < NKT) loadX(kt + 128);  // X[t+2]: in flight across next barrier
    }

    // mask from LDS (pre-scaled); quad lanes broadcast the same float4
    float4 mv[4];
#pragma unroll
    for (int nt = 0; nt < 4; ++nt)
      mv[nt] = *(const float4*)(Ml + kt + nt * 16 + quad * 4);

    // S^T = K.Q^T : D[key=nt*16+quad*4+r][q=l16]; P = exp2(S + mask)
    float p[2][4][4];
    __builtin_amdgcn_s_setprio(1);
#pragma unroll
    for (int nt = 0; nt < 4; ++nt) {
      const f16x8 kb0 = ld8(&Kl[buf][(nt * 16 + l16) * KP + quad * 8]);
      const f16x8 kb1 = ld8(&Kl[buf][(nt * 16 + l16) * KP + 32 + quad * 8]);
#pragma unroll
      for (int qt = 0; qt < 2; ++qt) {
        f32x4 s = z4;
        s = MFMA(kb0, aq0[qt], s);
        s = MFMA(kb1, aq1[qt], s);
        const float e0 = __builtin_amdgcn_exp2f(s[0] + mv[nt].x);
        const float e1 = __builtin_amdgcn_exp2f(s[1] + mv[nt].y);
        const float e2 = __builtin_amdgcn_exp2f(s[2] + mv[nt].z);
        const float e3 = __builtin_amdgcn_exp2f(s[3] + mv[nt].w);
        l_run[qt] += (e0 + e1) + (e2 + e3);
        p[qt][nt][0] = e0; p[qt][nt][1] = e1; p[qt][nt][2] = e2; p[qt][nt][3] = e3;
      }
    }
    __builtin_amdgcn_s_setprio(0);

    // P: C-layout -> A-layout, per-wave per-qt buffers; write both qt then
    // read both so the two LDS round-trip latencies overlap
#pragma unroll
    for (int qt = 0; qt < 2; ++qt)
#pragma unroll
      for (int nt = 0; nt < 4; ++nt)
        *(uint2*)&Pl[wave][qt][l16 * KP + nt * 16 + quad * 4] =
            pk4(p[qt][nt][0], p[qt][nt][1], p[qt][nt][2], p[qt][nt][3]);
    f16x8 ap0[2], ap1[2];
#pragma unroll
    for (int qt = 0; qt < 2; ++qt) {
      ap0[qt] = ld8(&Pl[wave][qt][l16 * KP + quad * 8]);
      ap1[qt] = ld8(&Pl[wave][qt][l16 * KP + 32 + quad * 8]);
    }

    // O^T += V.P^T : D[d=dt*16+quad*4+r][q=l16]
    __builtin_amdgcn_s_setprio(1);
#pragma unroll
    for (int dt = 0; dt < 4; ++dt) {
      const f16x8 vb0 = ld8(&Vl[buf][(dt * 16 + l16) * KP + quad * 8]);
      const f16x8 vb1 = ld8(&Vl[buf][(dt * 16 + l16) * KP + 32 + quad * 8]);
#pragma unroll
      for (int qt = 0; qt < 2; ++qt) {
        o[qt][dt] = MFMA(vb0, ap0[qt], o[qt][dt]);
        o[qt][dt] = MFMA(vb1, ap1[qt], o[qt][dt]);
      }
    }
    __builtin_amdgcn_s_setprio(0);

    lds_barrier();  // publishes KV[t+1]; guards buf reuse; X loads survive
  }

  // row-sum: lane covers its quad's 16 keys; finish across quads
  float inv[2];
#pragma unroll
  for (int qt = 0; qt < 2; ++qt) {
    float s = l_run[qt];
    s += __shfl_xor(s, 16);
    s += __shfl_xor(s, 32);
    inv[qt] = 1.f / s;
  }
  // ctx (token, h*64+d): lane's 4 d-values contiguous -> packed 8B stores
#pragma unroll
  for (int qt = 0; qt < 2; ++qt) {
    const int qg = qbase + wave * 32 + qt * 16 + l16;
    _Float16* base = ctx + (size_t)(b * LQ + qg) * HID + h * 64;
#pragma unroll
    for (int dt = 0; dt < 4; ++dt)
      *(uint2*)(base + dt * 16 + quad * 4) =
          pk4(o[qt][dt][0] * inv[qt], o[qt][dt][1] * inv[qt],
              o[qt][dt][2] * inv[qt], o[qt][dt][3] * inv[qt]);
  }
}

// ---------------------------------------------------------------------------
// W_lin fp32 -> fp16 (once; 2MB result stays L2-resident for linear_kernel)
// ---------------------------------------------------------------------------
__global__ __launch_bounds__(256) void wconv_kernel(const float* __restrict__ W,
                                                    _Float16* __restrict__ Wh) {
  const int i = blockIdx.x * 256 + threadIdx.x;
  const float4 v = ((const float4*)W)[i];
  ((uint2*)Wh)[i] = pk4(v.x, v.y, v.z, v.w);
}

// ---------------------------------------------------------------------------
// lin = ctx @ Wh^T + b; X = erf-GELU(lin) + resid. 128x128 tile, 512 threads
// (8 waves as 2x4), BK=64, double-buffered global_load_lds, 1 barrier/chunk.
// ---------------------------------------------------------------------------
__global__ __launch_bounds__(512) void linear_kernel(const _Float16* __restrict__ A,
                                                     const _Float16* __restrict__ Wh,
                                                     const float* __restrict__ bias,
                                                     const float* __restrict__ resid,
                                                     float* __restrict__ Xout) {
  __shared__ __align__(16) _Float16 Al[2][128 * 64];
  __shared__ __align__(16) _Float16 Bl[2][128 * 64];
  const int tid = threadIdx.x;
  const int wave = tid >> 6, lane = tid & 63, l16 = lane & 15, quad = lane >> 4;
  const int wm = wave >> 2, wn = wave & 3;
  const int nbase = blockIdx.x * 128, mbase = blockIdx.y * 128;
  const int srow = wave * 16 + (lane >> 3);
  const int sc = lane & 7;

  auto stage = [&](int kk, int nbuf) {
#pragma unroll
    for (int i = 0; i < 2; ++i) {
      const int row = srow + i * 8;
      const int c = sc ^ (row & 7);
      gl_lds16(A + (size_t)(mbase + row) * HID + kk + c * 8,
               &Al[nbuf][(wave * 16 + i * 8) * 64]);
      gl_lds16(Wh + (size_t)(nbase + row) * HID + kk + c * 8,
               &Bl[nbuf][(wave * 16 + i * 8) * 64]);
    }
  };

  const f32x4 z4 = {0.f, 0.f, 0.f, 0.f};
  f32x4 acc[4][2];
#pragma unroll
  for (int mt = 0; mt < 4; ++mt)
#pragma unroll
    for (int nt = 0; nt < 2; ++nt) acc[mt][nt] = z4;

  stage(0, 0);
  for (int t = 0; t < HID / 64; ++t) {
    const int buf = t & 1;
    __syncthreads();
    if (t + 1 < HID / 64) stage((t + 1) * 64, buf ^ 1);
    const int sw = l16 & 7;
    f16x8 b0[2], b1[2];
#pragma unroll
    for (int nt = 0; nt < 2; ++nt) {
      const int brow = wn * 32 + nt * 16 + l16;
      b0[nt] = ld8(&Bl[buf][brow * 64 + (quad ^ sw) * 8]);
      b1[nt] = ld8(&Bl[buf][brow * 64 + ((quad + 4) ^ sw) * 8]);
    }
#pragma unroll
    for (int mt = 0; mt < 4; ++mt) {
      const int arow = wm * 64 + mt * 16 + l16;
      const f16x8 a0 = ld8(&Al[buf][arow * 64 + (quad ^ sw) * 8]);
      const f16x8 a1 = ld8(&Al[buf][arow * 64 + ((quad + 4) ^ sw) * 8]);
#pragma unroll
      for (int nt = 0; nt < 2; ++nt) {
        acc[mt][nt] = MFMA(a0, b0[nt], acc[mt][nt]);
        acc[mt][nt] = MFMA(a1, b1[nt], acc[mt][nt]);
      }
    }
  }
#pragma unroll
  for (int nt = 0; nt < 2; ++nt) {
    const int col = nbase + wn * 32 + nt * 16 + l16;
    const float bv = bias[col];
#pragma unroll
    for (int mt = 0; mt < 4; ++mt) {
#pragma unroll
      for (int r = 0; r < 4; ++r) {
        const int row = mbase + wm * 64 + mt * 16 + quad * 4 + r;
        const float v = acc[mt][nt][r] + bv;
        const float g = 0.5f * v * (1.f + erff(v * 0.70710678118654752f));
        Xout[(size_t)row * HID + col] = g + resid[(size_t)row * HID + col];
      }
    }
  }
}

// ---------------------------------------------------------------------------
// LayerNorm over HID=1024 per token row.
// ---------------------------------------------------------------------------
__global__ __launch_bounds__(256) void ln_kernel(const float* __restrict__ X,
                                                 const float* __restrict__ gamma,
                                                 const float* __restrict__ beta,
                                                 float* __restrict__ out) {
  const int row = blockIdx.x, tid = threadIdx.x;
  const int lane = tid & 63, wave = tid >> 6;
  const float4 v = *(const float4*)(X + (size_t)row * HID + tid * 4);
  float s1 = v.x + v.y + v.z + v.w;
  float s2 = v.x * v.x + v.y * v.y + v.z * v.z + v.w * v.w;
#pragma unroll
  for (int off = 1; off < 64; off <<= 1) {
    s1 += __shfl_xor(s1, off);
    s2 += __shfl_xor(s2, off);
  }
  __shared__ float r1[4], r2[4];
  if (lane == 0) { r1[wave] = s1; r2[wave] = s2; }
  __syncthreads();
  s1 = r1[0] + r1[1] + r1[2] + r1[3];
  s2 = r2[0] + r2[1] + r2[2] + r2[3];
  const float mu = s1 * (1.f / HID);
  const float var = s2 * (1.f / HID) - mu * mu;
  const float rstd = rsqrtf(var + 1e-5f);
  const float4 g = *(const float4*)(gamma + tid * 4);
  const float4 be = *(const float4*)(beta + tid * 4);
  float4 ov;
  ov.x = (v.x - mu) * rstd * g.x + be.x;
  ov.y = (v.y - mu) * rstd * g.y + be.y;
  ov.z = (v.z - mu) * rstd * g.z + be.z;
  ov.w = (v.w - mu) * rstd * g.w + be.w;
  *(float4*)(out + (size_t)row * HID + tid * 4) = ov;
}

// ---------------------------------------------------------------------------
// Workspace:
//   ctx fp16 [ 0, 8M)
//   Xb  fp32 [ 8M,24M)
//   Wh  fp16 [24M,26M)
// ---------------------------------------------------------------------------
extern "C" void kernel_launch(void* const* d_in, const int* in_sizes, int n_in,
                              void* d_out, int out_size, void* d_ws, size_t ws_size,
                              hipStream_t stream) {
  (void)in_sizes; (void)n_in; (void)out_size; (void)ws_size;
  const float* input_embed = (const float*)d_in[0];
  const float* kg_embed    = (const float*)d_in[1];
  // d_in[2] = input_mask: additive per-query constant -> softmax-invariant, unused
  const float* kg_mask = (const float*)d_in[3];
  const float* Wq    = (const float*)d_in[4];
  const float* Wk    = (const float*)d_in[5];
  const float* Wv    = (const float*)d_in[6];
  const float* W_lin = (const float*)d_in[7];
  const float* b_lin = (const float*)d_in[8];
  const float* gamma = (const float*)d_in[9];
  const float* beta  = (const float*)d_in[10];

  char* ws = (char*)d_ws;
  _Float16* ctx = (_Float16*)(ws);
  float*    Xb  = (float*)(ws + (8u << 20));
  _Float16* Wh  = (_Float16*)(ws + (24u << 20));

  attn_kernel<<<dim3(128, 2), dim3(512), 0, stream>>>(input_embed, kg_embed, Wq, Wk, Wv,
                                                      kg_mask, ctx);
  wconv_kernel<<<dim3(1024), dim3(256), 0, stream>>>(W_lin, Wh);
  linear_kernel<<<dim3(8, 32), dim3(512), 0, stream>>>(ctx, Wh, b_lin, input_embed, Xb);
  ln_kernel<<<dim3(NTOK), dim3(256), 0, stream>>>(Xb, gamma, beta, (float*)d_out);
}

// Round 6
// 216.658 us; speedup vs baseline: 2.0501x; 1.4610x over previous
//
#include <hip/hip_runtime.h>
#include <cstdint>

#define BATCH 8
#define LQ 512
#define LK 2048
#define NH 16
#define DIM 64
#define HID 1024
#define NTOK (BATCH * LQ)   // 4096 tokens
#define NKT (LK / 64)       // 32 key tiles
#define KP 72               // pad: 144B row stride, 16B-aligned (R5 lesson: pad % 8 == 0!)
#define SC 0.1803368801111204f    // 0.125 * log2(e): folded into Q at pack time
#define NEGM (-1.4426950408889634e8f)  // -1e8 * log2(e): key-mask in exp2 domain

typedef _Float16 f16x8 __attribute__((ext_vector_type(8)));
typedef __fp16 half2v __attribute__((ext_vector_type(2)));
typedef float f32x4 __attribute__((ext_vector_type(4)));

#define MFMA(a, b, c) __builtin_amdgcn_mfma_f32_16x16x32_f16((a), (b), (c), 0, 0, 0)

__device__ __forceinline__ f16x8 ld8(const _Float16* p) { return *(const f16x8*)p; }

// async global->LDS, 16B per lane; lds dst is wave-uniform base (HW adds lane*16)
__device__ __forceinline__ void gl_lds16(const void* g, void* l) {
  __builtin_amdgcn_global_load_lds(
      (const __attribute__((address_space(1))) uint32_t*)g,
      (__attribute__((address_space(3))) uint32_t*)l, 16, 0, 0);
}

// LDS flush + barrier that does NOT drain vmcnt: in-flight global->VGPR
// loads survive (HK/m194 idiom).
__device__ __forceinline__ void lds_barrier() {
  asm volatile("s_waitcnt lgkmcnt(0)" ::: "memory");
  __builtin_amdgcn_s_barrier();
}

// 8 consecutive fp32 -> fp16 fragment (RTE scalar casts)
__device__ __forceinline__ f16x8 cvt8(const float* p) {
  const float4 a = *(const float4*)p;
  const float4 b = *(const float4*)(p + 4);
  f16x8 v;
  v[0] = (_Float16)a.x; v[1] = (_Float16)a.y; v[2] = (_Float16)a.z; v[3] = (_Float16)a.w;
  v[4] = (_Float16)b.x; v[5] = (_Float16)b.y; v[6] = (_Float16)b.z; v[7] = (_Float16)b.w;
  return v;
}

// pack 4 fp32 -> 4 fp16 (2x v_cvt_pkrtz) for ds_write_b64
__device__ __forceinline__ uint2 pk4(float a, float b, float c, float d) {
  union { half2v h2[2]; uint2 u; } t;
  t.h2[0] = __builtin_amdgcn_cvt_pkrtz(a, b);
  t.h2[1] = __builtin_amdgcn_cvt_pkrtz(c, d);
  return t.u;
}

// two float4 -> f16x8 via pkrtz
__device__ __forceinline__ f16x8 pk8(float4 a, float4 b) {
  union { half2v h2[4]; f16x8 v; } t;
  t.h2[0] = __builtin_amdgcn_cvt_pkrtz(a.x, a.y);
  t.h2[1] = __builtin_amdgcn_cvt_pkrtz(a.z, a.w);
  t.h2[2] = __builtin_amdgcn_cvt_pkrtz(b.x, b.y);
  t.h2[3] = __builtin_amdgcn_cvt_pkrtz(b.z, b.w);
  return t.v;
}

// ---------------------------------------------------------------------------
// Fully fused attention: Q/K/V projections + flash attention in one kernel.
// ROUND 6: TEST THE 64KB LDS / 1-WG-PER-CU HYPOTHESIS. Every config this
// session used >64KB LDS/WG and never co-scheduled 2 WGs/CU (occupancy ~20%,
// R4 wall-clock confirms) despite LDS*2<=160KB and VGPR<=128. Hypothesis:
// >64KB LDS caps a CU at 1 WG. This version single-buffers Kl/Vl -> LDS
// total 62KB (9+9+36+8). Cost: 2 lgkm-barriers/tile and no intra-block
// proj(t+1)/compute(t) overlap. Gain if hypothesis holds: 2 co-resident
// blocks/CU with DECOUPLED barriers = the cross-block latency cover this
// latency-bound kernel (MfmaUtil 21/VALU 30/occ 20/HBM 8) has been missing.
// R5 lesson applied: KP=72 (16B-aligned rows; conflicts proven off-path).
// Per (b,h) x 256-q block: grid (128,2), 512 thr / 8 waves. Wave-specialized
// projections (waves 0-3: K, 4-7: V), reg-staged X, setprio on MFMA.
// ---------------------------------------------------------------------------
__global__ __launch_bounds__(512, 2) void attn_kernel(
    const float* __restrict__ Xq, const float* __restrict__ Xk,
    const float* __restrict__ Wq, const float* __restrict__ Wk,
    const float* __restrict__ Wv, const float* __restrict__ kg_mask,
    _Float16* __restrict__ ctx) {
  __shared__ __align__(16) _Float16 Kl[64 * KP];       // 9 KB:  [key][e]
  __shared__ __align__(16) _Float16 Vl[64 * KP];       // 9 KB:  [d][key]
  __shared__ __align__(16) _Float16 Pl[8][2][16 * KP]; // 36 KB: per-wave/qt P transpose
  __shared__ __align__(16) float    Ml[LK];            // 8 KB:  (1-mask)*NEGM
  const int tid = threadIdx.x;
  const int wave = tid >> 6, lane = tid & 63, l16 = lane & 15, quad = lane >> 4;
  const int kw = wave & 3;  // row-group for X/K/V projection work
  const int b = blockIdx.x >> 4, h = blockIdx.x & 15;
  const int qbase = blockIdx.y * 256;
  const float* Xg = Xk + (size_t)b * LK * HID + h * 64;  // key-side X, this head's cols
  const float* mg = kg_mask + (size_t)b * LK;

  // X register staging: lane (quad,l16) of wave kw holds row kw*16+l16,
  // logical chunks 2q,2q+1 (floats 8q..8q+7) and 2q+8,2q+9 (8q+32..8q+39).
  const float* xrow0 = Xg + (size_t)(kw * 16 + l16) * HID + quad * 8;
  float4 xf0, xf1, xf2, xf3;
  auto loadX = [&](int kt) {
    const float* xr = xrow0 + (size_t)kt * HID;
    xf0 = *(const float4*)(xr);
    xf1 = *(const float4*)(xr + 4);
    xf2 = *(const float4*)(xr + 32);
    xf3 = *(const float4*)(xr + 36);
  };
  loadX(0);  // in flight across the whole prologue

  // mask pre-scale into LDS: 512 threads x float4 covers LK=2048 exactly.
  // Published by barrier B of tile 0.
  {
    const float4 m4 = *(const float4*)(mg + tid * 4);
    float4 mo;
    mo.x = (1.f - m4.x) * NEGM;
    mo.y = (1.f - m4.y) * NEGM;
    mo.z = (1.f - m4.z) * NEGM;
    mo.w = (1.f - m4.w) * NEGM;
    *(float4*)(Ml + tid * 4) = mo;
  }

  // ---- fused Q projection: D[d_out][q] = Wq . Xq^T, scaled by SC ----
  f16x8 aq0[2], aq1[2];
  {
    f16x8 wq0[4], wq1[4];
#pragma unroll
    for (int nt = 0; nt < 4; ++nt) {
      const float* wp = Wq + (nt * 16 + l16) * DIM + quad * 8;
      wq0[nt] = cvt8(wp);
      wq1[nt] = cvt8(wp + 32);
    }
#pragma unroll
    for (int qt = 0; qt < 2; ++qt) {
      const int qg = qbase + wave * 32 + qt * 16 + l16;
      const float* xpq = Xq + (size_t)(b * LQ + qg) * HID + h * 64 + quad * 8;
      const f16x8 bq0 = cvt8(xpq), bq1 = cvt8(xpq + 32);
#pragma unroll
      for (int nt = 0; nt < 4; ++nt) {
        f32x4 d = {0.f, 0.f, 0.f, 0.f};
        d = MFMA(wq0[nt], bq0, d);
        d = MFMA(wq1[nt], bq1, d);
        *(uint2*)&Pl[wave][qt][l16 * KP + nt * 16 + quad * 4] =
            pk4(d[0] * SC, d[1] * SC, d[2] * SC, d[3] * SC);
      }
      aq0[qt] = ld8(&Pl[wave][qt][l16 * KP + quad * 8]);
      aq1[qt] = ld8(&Pl[wave][qt][l16 * KP + 32 + quad * 8]);
    }
  }

  // ---- projection weight fragments, once per block: waves 0-3 hold Wk
  // (A-operand of K proj), waves 4-7 hold Wv (B-operand of V proj). ----
  const float* Wsel = (wave < 4) ? Wk : Wv;
  f16x8 aw0[4], aw1[4];
#pragma unroll
  for (int nt = 0; nt < 4; ++nt) {
    const float* wp = Wsel + (nt * 16 + l16) * DIM + quad * 8;
    aw0[nt] = cvt8(wp);
    aw1[nt] = cvt8(wp + 32);
  }

  const f32x4 z4 = {0.f, 0.f, 0.f, 0.f};
  f32x4 o[2][4];
  float l_run[2] = {0.f, 0.f};
#pragma unroll
  for (int qt = 0; qt < 2; ++qt)
#pragma unroll
    for (int i = 0; i < 4; ++i) o[qt][i] = z4;

  for (int t = 0; t < NKT; ++t) {
    const int kt = t * 64;

    lds_barrier();  // A: guards Kl/Vl overwrite vs previous tile's reads

    // ---- proj(t): X[t] (in xf, counted vmcnt wait at pk8) -> Kl/Vl ----
    {
      const f16x8 bx0 = pk8(xf0, xf1), bx1 = pk8(xf2, xf3);
      if (wave < 4) {
#pragma unroll
        for (int nt = 0; nt < 4; ++nt) {
          f32x4 d = z4;
          d = MFMA(aw0[nt], bx0, d);
          d = MFMA(aw1[nt], bx1, d);
          *(uint2*)&Kl[(kw * 16 + l16) * KP + nt * 16 + quad * 4] =
              pk4(d[0], d[1], d[2], d[3]);
        }
      } else {
#pragma unroll
        for (int dt = 0; dt < 4; ++dt) {
          f32x4 d = z4;
          d = MFMA(bx0, aw0[dt], d);
          d = MFMA(bx1, aw1[dt], d);
          *(uint2*)&Vl[(dt * 16 + l16) * KP + kw * 16 + quad * 4] =
              pk4(d[0], d[1], d[2], d[3]);
        }
      }
    }
    if (t + 1 < NKT) loadX(kt + 64);  // X[t+1]: in flight across barrier B

    lds_barrier();  // B: publishes Kl/Vl (and Ml on t=0); X loads survive

    // mask from LDS (pre-scaled); quad lanes broadcast the same float4
    float4 mv[4];
#pragma unroll
    for (int nt = 0; nt < 4; ++nt)
      mv[nt] = *(const float4*)(Ml + kt + nt * 16 + quad * 4);

    // S^T = K.Q^T : D[key=nt*16+quad*4+r][q=l16]; P = exp2(S + mask)
    float p[2][4][4];
    __builtin_amdgcn_s_setprio(1);
#pragma unroll
    for (int nt = 0; nt < 4; ++nt) {
      const f16x8 kb0 = ld8(&Kl[(nt * 16 + l16) * KP + quad * 8]);
      const f16x8 kb1 = ld8(&Kl[(nt * 16 + l16) * KP + 32 + quad * 8]);
#pragma unroll
      for (int qt = 0; qt < 2; ++qt) {
        f32x4 s = z4;
        s = MFMA(kb0, aq0[qt], s);
        s = MFMA(kb1, aq1[qt], s);
        const float e0 = __builtin_amdgcn_exp2f(s[0] + mv[nt].x);
        const float e1 = __builtin_amdgcn_exp2f(s[1] + mv[nt].y);
        const float e2 = __builtin_amdgcn_exp2f(s[2] + mv[nt].z);
        const float e3 = __builtin_amdgcn_exp2f(s[3] + mv[nt].w);
        l_run[qt] += (e0 + e1) + (e2 + e3);
        p[qt][nt][0] = e0; p[qt][nt][1] = e1; p[qt][nt][2] = e2; p[qt][nt][3] = e3;
      }
    }
    __builtin_amdgcn_s_setprio(0);

    // P: C-layout -> A-layout, per-wave per-qt buffers; write both qt then
    // read both so the two LDS round-trip latencies overlap
#pragma unroll
    for (int qt = 0; qt < 2; ++qt)
#pragma unroll
      for (int nt = 0; nt < 4; ++nt)
        *(uint2*)&Pl[wave][qt][l16 * KP + nt * 16 + quad * 4] =
            pk4(p[qt][nt][0], p[qt][nt][1], p[qt][nt][2], p[qt][nt][3]);
    f16x8 ap0[2], ap1[2];
#pragma unroll
    for (int qt = 0; qt < 2; ++qt) {
      ap0[qt] = ld8(&Pl[wave][qt][l16 * KP + quad * 8]);
      ap1[qt] = ld8(&Pl[wave][qt][l16 * KP + 32 + quad * 8]);
    }

    // O^T += V.P^T : D[d=dt*16+quad*4+r][q=l16]
    __builtin_amdgcn_s_setprio(1);
#pragma unroll
    for (int dt = 0; dt < 4; ++dt) {
      const f16x8 vb0 = ld8(&Vl[(dt * 16 + l16) * KP + quad * 8]);
      const f16x8 vb1 = ld8(&Vl[(dt * 16 + l16) * KP + 32 + quad * 8]);
#pragma unroll
      for (int qt = 0; qt < 2; ++qt) {
        o[qt][dt] = MFMA(vb0, ap0[qt], o[qt][dt]);
        o[qt][dt] = MFMA(vb1, ap1[qt], o[qt][dt]);
      }
    }
    __builtin_amdgcn_s_setprio(0);
  }

  // row-sum: lane covers its quad's 16 keys; finish across quads
  float inv[2];
#pragma unroll
  for (int qt = 0; qt < 2; ++qt) {
    float s = l_run[qt];
    s += __shfl_xor(s, 16);
    s += __shfl_xor(s, 32);
    inv[qt] = 1.f / s;
  }
  // ctx (token, h*64+d): lane's 4 d-values contiguous -> packed 8B stores
#pragma unroll
  for (int qt = 0; qt < 2; ++qt) {
    const int qg = qbase + wave * 32 + qt * 16 + l16;
    _Float16* base = ctx + (size_t)(b * LQ + qg) * HID + h * 64;
#pragma unroll
    for (int dt = 0; dt < 4; ++dt)
      *(uint2*)(base + dt * 16 + quad * 4) =
          pk4(o[qt][dt][0] * inv[qt], o[qt][dt][1] * inv[qt],
              o[qt][dt][2] * inv[qt], o[qt][dt][3] * inv[qt]);
  }
}

// ---------------------------------------------------------------------------
// W_lin fp32 -> fp16 (once; 2MB result stays L2-resident for linear_kernel)
// ---------------------------------------------------------------------------
__global__ __launch_bounds__(256) void wconv_kernel(const float* __restrict__ W,
                                                    _Float16* __restrict__ Wh) {
  const int i = blockIdx.x * 256 + threadIdx.x;
  const float4 v = ((const float4*)W)[i];
  ((uint2*)Wh)[i] = pk4(v.x, v.y, v.z, v.w);
}

// ---------------------------------------------------------------------------
// lin = ctx @ Wh^T + b; X = erf-GELU(lin) + resid. 128x128 tile, 512 threads
// (8 waves as 2x4), BK=64, double-buffered global_load_lds, 1 barrier/chunk.
// ---------------------------------------------------------------------------
__global__ __launch_bounds__(512) void linear_kernel(const _Float16* __restrict__ A,
                                                     const _Float16* __restrict__ Wh,
                                                     const float* __restrict__ bias,
                                                     const float* __restrict__ resid,
                                                     float* __restrict__ Xout) {
  __shared__ __align__(16) _Float16 Al[2][128 * 64];
  __shared__ __align__(16) _Float16 Bl[2][128 * 64];
  const int tid = threadIdx.x;
  const int wave = tid >> 6, lane = tid & 63, l16 = lane & 15, quad = lane >> 4;
  const int wm = wave >> 2, wn = wave & 3;
  const int nbase = blockIdx.x * 128, mbase = blockIdx.y * 128;
  const int srow = wave * 16 + (lane >> 3);
  const int sc = lane & 7;

  auto stage = [&](int kk, int nbuf) {
#pragma unroll
    for (int i = 0; i < 2; ++i) {
      const int row = srow + i * 8;
      const int c = sc ^ (row & 7);
      gl_lds16(A + (size_t)(mbase + row) * HID + kk + c * 8,
               &Al[nbuf][(wave * 16 + i * 8) * 64]);
      gl_lds16(Wh + (size_t)(nbase + row) * HID + kk + c * 8,
               &Bl[nbuf][(wave * 16 + i * 8) * 64]);
    }
  };

  const f32x4 z4 = {0.f, 0.f, 0.f, 0.f};
  f32x4 acc[4][2];
#pragma unroll
  for (int mt = 0; mt < 4; ++mt)
#pragma unroll
    for (int nt = 0; nt < 2; ++nt) acc[mt][nt] = z4;

  stage(0, 0);
  for (int t = 0; t < HID / 64; ++t) {
    const int buf = t & 1;
    __syncthreads();
    if (t + 1 < HID / 64) stage((t + 1) * 64, buf ^ 1);
    const int sw = l16 & 7;
    f16x8 b0[2], b1[2];
#pragma unroll
    for (int nt = 0; nt < 2; ++nt) {
      const int brow = wn * 32 + nt * 16 + l16;
      b0[nt] = ld8(&Bl[buf][brow * 64 + (quad ^ sw) * 8]);
      b1[nt] = ld8(&Bl[buf][brow * 64 + ((quad + 4) ^ sw) * 8]);
    }
#pragma unroll
    for (int mt = 0; mt < 4; ++mt) {
      const int arow = wm * 64 + mt * 16 + l16;
      const f16x8 a0 = ld8(&Al[buf][arow * 64 + (quad ^ sw) * 8]);
      const f16x8 a1 = ld8(&Al[buf][arow * 64 + ((quad + 4) ^ sw) * 8]);
#pragma unroll
      for (int nt = 0; nt < 2; ++nt) {
        acc[mt][nt] = MFMA(a0, b0[nt], acc[mt][nt]);
        acc[mt][nt] = MFMA(a1, b1[nt], acc[mt][nt]);
      }
    }
  }
#pragma unroll
  for (int nt = 0; nt < 2; ++nt) {
    const int col = nbase + wn * 32 + nt * 16 + l16;
    const float bv = bias[col];
#pragma unroll
    for (int mt = 0; mt < 4; ++mt) {
#pragma unroll
      for (int r = 0; r < 4; ++r) {
        const int row = mbase + wm * 64 + mt * 16 + quad * 4 + r;
        const float v = acc[mt][nt][r] + bv;
        const float g = 0.5f * v * (1.f + erff(v * 0.70710678118654752f));
        Xout[(size_t)row * HID + col] = g + resid[(size_t)row * HID + col];
      }
    }
  }
}

// ---------------------------------------------------------------------------
// LayerNorm over HID=1024 per token row.
// ---------------------------------------------------------------------------
__global__ __launch_bounds__(256) void ln_kernel(const float* __restrict__ X,
                                                 const float* __restrict__ gamma,
                                                 const float* __restrict__ beta,
                                                 float* __restrict__ out) {
  const int row = blockIdx.x, tid = threadIdx.x;
  const int lane = tid & 63, wave = tid >> 6;
  const float4 v = *(const float4*)(X + (size_t)row * HID + tid * 4);
  float s1 = v.x + v.y + v.z + v.w;
  float s2 = v.x * v.x + v.y * v.y + v.z * v.z + v.w * v.w;
#pragma unroll
  for (int off = 1; off < 64; off <<= 1) {
    s1 += __shfl_xor(s1, off);
    s2 += __shfl_xor(s2, off);
  }
  __shared__ float r1[4], r2[4];
  if (lane == 0) { r1[wave] = s1; r2[wave] = s2; }
  __syncthreads();
  s1 = r1[0] + r1[1] + r1[2] + r1[3];
  s2 = r2[0] + r2[1] + r2[2] + r2[3];
  const float mu = s1 * (1.f / HID);
  const float var = s2 * (1.f / HID) - mu * mu;
  const float rstd = rsqrtf(var + 1e-5f);
  const float4 g = *(const float4*)(gamma + tid * 4);
  const float4 be = *(const float4*)(beta + tid * 4);
  float4 ov;
  ov.x = (v.x - mu) * rstd * g.x + be.x;
  ov.y = (v.y - mu) * rstd * g.y + be.y;
  ov.z = (v.z - mu) * rstd * g.z + be.z;
  ov.w = (v.w - mu) * rstd * g.w + be.w;
  *(float4*)(out + (size_t)row * HID + tid * 4) = ov;
}

// ---------------------------------------------------------------------------
// Workspace:
//   ctx fp16 [ 0, 8M)
//   Xb  fp32 [ 8M,24M)
//   Wh  fp16 [24M,26M)
// ---------------------------------------------------------------------------
extern "C" void kernel_launch(void* const* d_in, const int* in_sizes, int n_in,
                              void* d_out, int out_size, void* d_ws, size_t ws_size,
                              hipStream_t stream) {
  (void)in_sizes; (void)n_in; (void)out_size; (void)ws_size;
  const float* input_embed = (const float*)d_in[0];
  const float* kg_embed    = (const float*)d_in[1];
  // d_in[2] = input_mask: additive per-query constant -> softmax-invariant, unused
  const float* kg_mask = (const float*)d_in[3];
  const float* Wq    = (const float*)d_in[4];
  const float* Wk    = (const float*)d_in[5];
  const float* Wv    = (const float*)d_in[6];
  const float* W_lin = (const float*)d_in[7];
  const float* b_lin = (const float*)d_in[8];
  const float* gamma = (const float*)d_in[9];
  const float* beta  = (const float*)d_in[10];

  char* ws = (char*)d_ws;
  _Float16* ctx = (_Float16*)(ws);
  float*    Xb  = (float*)(ws + (8u << 20));
  _Float16* Wh  = (_Float16*)(ws + (24u << 20));

  attn_kernel<<<dim3(128, 2), dim3(512), 0, stream>>>(input_embed, kg_embed, Wq, Wk, Wv,
                                                      kg_mask, ctx);
  wconv_kernel<<<dim3(1024), dim3(256), 0, stream>>>(W_lin, Wh);
  linear_kernel<<<dim3(8, 32), dim3(512), 0, stream>>>(ctx, Wh, b_lin, input_embed, Xb);
  ln_kernel<<<dim3(NTOK), dim3(256), 0, stream>>>(Xb, gamma, beta, (float*)d_out);
}